// Round 6
// baseline (1397.857 us; speedup 1.0000x reference)
//
#include <hip/hip_runtime.h>
#include <math.h>

#define SCAN_BLK 256

// ---------------- CSR build ----------------
__global__ void count_kernel(const int* __restrict__ ei, int* __restrict__ deg, int E) {
    int e = blockIdx.x * blockDim.x + threadIdx.x;
    if (e < E) atomicAdd(&deg[ei[E + e]], 1);
}

__global__ void scan1_kernel(const int* __restrict__ deg, int* __restrict__ part,
                             int* __restrict__ bsum, int N) {
    __shared__ int sm[SCAN_BLK];
    int i = blockIdx.x * SCAN_BLK + threadIdx.x;
    int v = (i < N) ? deg[i] : 0;
    sm[threadIdx.x] = v;
    __syncthreads();
    for (int off = 1; off < SCAN_BLK; off <<= 1) {
        int t = (threadIdx.x >= off) ? sm[threadIdx.x - off] : 0;
        __syncthreads();
        sm[threadIdx.x] += t;
        __syncthreads();
    }
    if (i < N) part[i] = sm[threadIdx.x] - v;
    if (threadIdx.x == SCAN_BLK - 1) bsum[blockIdx.x] = sm[threadIdx.x];
}

__global__ void scan2_kernel(const int* __restrict__ bsum, int* __restrict__ boff, int nb) {
    __shared__ int sm[512];
    int v = (threadIdx.x < nb) ? bsum[threadIdx.x] : 0;
    sm[threadIdx.x] = v;
    __syncthreads();
    for (int off = 1; off < 512; off <<= 1) {
        int t = (threadIdx.x >= off) ? sm[threadIdx.x - off] : 0;
        __syncthreads();
        sm[threadIdx.x] += t;
        __syncthreads();
    }
    if (threadIdx.x < nb) boff[threadIdx.x] = sm[threadIdx.x] - v;
}

__global__ void scan3_kernel(int* __restrict__ rowptr, const int* __restrict__ boff,
                             int N, int E) {
    int i = blockIdx.x * blockDim.x + threadIdx.x;
    if (i < N) rowptr[i] += boff[i / SCAN_BLK];
    if (i == 0) rowptr[N] = E;
}

// scatter only the 4B edge id (minimal scattered-write traffic)
__global__ void scatterE_kernel(const int* __restrict__ ei, const int* __restrict__ rowptr,
                                int* __restrict__ cursor, int* __restrict__ srcp, int E) {
    int e = blockIdx.x * blockDim.x + threadIdx.x;
    if (e >= E) return;
    int dst = ei[E + e];
    int pos = atomicAdd(&cursor[dst], 1);
    srcp[rowptr[dst] + pos] = e;       // temporarily holds eid
}

// gather-permute: coalesced writes; random 32B ea reads absorbed by L3.
// srcp[j]: eid -> src (in-place, read-before-write within thread)
__global__ void permuteE_kernel(const int* __restrict__ ei, const float* __restrict__ ea,
                                int* __restrict__ srcp, float* __restrict__ eap, int E) {
    int j = blockIdx.x * blockDim.x + threadIdx.x;
    if (j >= E) return;
    int e = srcp[j];
    float4 a0 = *(const float4*)(ea + (size_t)e * 8);
    float4 a1 = *(const float4*)(ea + (size_t)e * 8 + 4);
    *(float4*)(eap + (size_t)j * 8)     = a0;
    *(float4*)(eap + (size_t)j * 8 + 4) = a1;
    srcp[j] = ei[e];
}

// scatter fallback: rec[idx] = (src, eid)
__global__ void scatterR_kernel(const int* __restrict__ ei, const int* __restrict__ rowptr,
                                int* __restrict__ cursor, int2* __restrict__ rec, int E) {
    int e = blockIdx.x * blockDim.x + threadIdx.x;
    if (e >= E) return;
    int dst = ei[E + e];
    int pos = atomicAdd(&cursor[dst], 1);
    rec[rowptr[dst] + pos] = make_int2(ei[e], e);
}

// ------- node projections: Q,K,V (head-padded layout), S (unpadded) -------
template<int CIN, int H, int C, int CP>
__global__ void proj_kernel(const float* __restrict__ X,
                            const float* __restrict__ wq, const float* __restrict__ bq,
                            const float* __restrict__ wk, const float* __restrict__ bk,
                            const float* __restrict__ wv, const float* __restrict__ bv,
                            const float* __restrict__ wsk, const float* __restrict__ bsk,
                            float* __restrict__ Q, float* __restrict__ K,
                            float* __restrict__ V, float* __restrict__ S, int N)
{
    const int HC = H * C;
    int idx = blockIdx.x * blockDim.x + threadIdx.x;
    if (idx >= N * HC) return;
    int n = idx / HC;
    int c = idx - n * HC;
    int h = c / C;
    int cc = c - h * C;
    float q = bq[c], k = bk[c], v = bv[c], s = bsk[c];
    const float* xr = X + (size_t)n * CIN;
#pragma unroll
    for (int i = 0; i < CIN; ++i) {
        float xi = xr[i];
        q = fmaf(xi, wq[i * HC + c], q);
        k = fmaf(xi, wk[i * HC + c], k);
        v = fmaf(xi, wv[i * HC + c], v);
        s = fmaf(xi, wsk[i * HC + c], s);
    }
    size_t po = (size_t)n * (H * CP) + h * CP + cc;
    Q[po] = q; K[po] = k; V[po] = v;
    S[(size_t)n * HC + c] = s;
}

// ---- fused gather+gate, H=8: thread per (node, head), factorized e -----
template<int C, int CP, bool PERM>
__global__ void gather8f_kernel(const int* __restrict__ rowptr,
                                const int* __restrict__ srcp,
                                const int2* __restrict__ rec,
                                const float* __restrict__ eap,
                                const float* __restrict__ ea,
                                const float* __restrict__ we,
                                const float* __restrict__ Q,
                                const float* __restrict__ K,
                                const float* __restrict__ V,
                                const float* __restrict__ S,
                                const float* __restrict__ wb,
                                float* __restrict__ OUT,
                                int N, float scale)
{
    const int HC = 8 * C;
    const int HCP = 8 * CP;
    int tid = blockIdx.x * blockDim.x + threadIdx.x;
    int n = tid >> 3;
    int h = tid & 7;
    if (n >= N) return;

    float q[C];
    const float* Qp = Q + (size_t)n * HCP + h * CP;
#pragma unroll
    for (int c = 0; c < C; ++c) q[c] = Qp[c];

    float qe[8];
#pragma unroll
    for (int d = 0; d < 8; ++d) {
        float t = 0.f;
#pragma unroll
        for (int c = 0; c < C; ++c) t = fmaf(we[d * HC + h * C + c], q[c], t);
        qe[d] = t;
    }

    float num[C];
#pragma unroll
    for (int c = 0; c < C; ++c) num[c] = 0.f;
    float sacc[8];
#pragma unroll
    for (int d = 0; d < 8; ++d) sacc[d] = 0.f;
    float den = 0.f;

    int rs = rowptr[n], re = rowptr[n + 1];
    int j = rs;
    for (; j + 1 < re; j += 2) {
        int s0, s1;
        const float *A0, *A1;
        if (PERM) {
            s0 = srcp[j]; s1 = srcp[j + 1];
            A0 = eap + (size_t)j * 8; A1 = eap + (size_t)(j + 1) * 8;
        } else {
            int2 r0 = rec[j], r1 = rec[j + 1];
            s0 = r0.x; s1 = r1.x;
            A0 = ea + (size_t)r0.y * 8; A1 = ea + (size_t)r1.y * 8;
        }
        float4 a00 = *(const float4*)A0;
        float4 a01 = *(const float4*)(A0 + 4);
        float4 a10 = *(const float4*)A1;
        float4 a11 = *(const float4*)(A1 + 4);
        const float* K0 = K + (size_t)s0 * HCP + h * CP;
        const float* V0 = V + (size_t)s0 * HCP + h * CP;
        const float* K1 = K + (size_t)s1 * HCP + h * CP;
        const float* V1 = V + (size_t)s1 * HCP + h * CP;
        float k0[CP], v0[CP], k1[CP], v1[CP];
#pragma unroll
        for (int t4 = 0; t4 < CP / 4; ++t4) {
            *(float4*)(k0 + 4 * t4) = *(const float4*)(K0 + 4 * t4);
            *(float4*)(v0 + 4 * t4) = *(const float4*)(V0 + 4 * t4);
            *(float4*)(k1 + 4 * t4) = *(const float4*)(K1 + 4 * t4);
            *(float4*)(v1 + 4 * t4) = *(const float4*)(V1 + 4 * t4);
        }
        float d0 = 0.f, d1 = 0.f;
#pragma unroll
        for (int c = 0; c < C; ++c) {
            d0 = fmaf(q[c], k0[c], d0);
            d1 = fmaf(q[c], k1[c], d1);
        }
        float qa0 = qe[0] * a00.x;
        qa0 = fmaf(qe[1], a00.y, qa0); qa0 = fmaf(qe[2], a00.z, qa0);
        qa0 = fmaf(qe[3], a00.w, qa0); qa0 = fmaf(qe[4], a01.x, qa0);
        qa0 = fmaf(qe[5], a01.y, qa0); qa0 = fmaf(qe[6], a01.z, qa0);
        qa0 = fmaf(qe[7], a01.w, qa0);
        float qa1 = qe[0] * a10.x;
        qa1 = fmaf(qe[1], a10.y, qa1); qa1 = fmaf(qe[2], a10.z, qa1);
        qa1 = fmaf(qe[3], a10.w, qa1); qa1 = fmaf(qe[4], a11.x, qa1);
        qa1 = fmaf(qe[5], a11.y, qa1); qa1 = fmaf(qe[6], a11.z, qa1);
        qa1 = fmaf(qe[7], a11.w, qa1);
        float ex0 = __expf((d0 + qa0) * scale);
        float ex1 = __expf((d1 + qa1) * scale);
        den += ex0 + ex1;
#pragma unroll
        for (int c = 0; c < C; ++c) {
            num[c] = fmaf(ex0, v0[c], num[c]);
            num[c] = fmaf(ex1, v1[c], num[c]);
        }
        sacc[0] = fmaf(ex0, a00.x, fmaf(ex1, a10.x, sacc[0]));
        sacc[1] = fmaf(ex0, a00.y, fmaf(ex1, a10.y, sacc[1]));
        sacc[2] = fmaf(ex0, a00.z, fmaf(ex1, a10.z, sacc[2]));
        sacc[3] = fmaf(ex0, a00.w, fmaf(ex1, a10.w, sacc[3]));
        sacc[4] = fmaf(ex0, a01.x, fmaf(ex1, a11.x, sacc[4]));
        sacc[5] = fmaf(ex0, a01.y, fmaf(ex1, a11.y, sacc[5]));
        sacc[6] = fmaf(ex0, a01.z, fmaf(ex1, a11.z, sacc[6]));
        sacc[7] = fmaf(ex0, a01.w, fmaf(ex1, a11.w, sacc[7]));
    }
    if (j < re) {
        int s0;
        const float* A0;
        if (PERM) {
            s0 = srcp[j];
            A0 = eap + (size_t)j * 8;
        } else {
            int2 r0 = rec[j];
            s0 = r0.x;
            A0 = ea + (size_t)r0.y * 8;
        }
        float4 a00 = *(const float4*)A0;
        float4 a01 = *(const float4*)(A0 + 4);
        const float* K0 = K + (size_t)s0 * HCP + h * CP;
        const float* V0 = V + (size_t)s0 * HCP + h * CP;
        float k0[CP], v0[CP];
#pragma unroll
        for (int t4 = 0; t4 < CP / 4; ++t4) {
            *(float4*)(k0 + 4 * t4) = *(const float4*)(K0 + 4 * t4);
            *(float4*)(v0 + 4 * t4) = *(const float4*)(V0 + 4 * t4);
        }
        float d0 = 0.f;
#pragma unroll
        for (int c = 0; c < C; ++c) d0 = fmaf(q[c], k0[c], d0);
        float qa0 = qe[0] * a00.x;
        qa0 = fmaf(qe[1], a00.y, qa0); qa0 = fmaf(qe[2], a00.z, qa0);
        qa0 = fmaf(qe[3], a00.w, qa0); qa0 = fmaf(qe[4], a01.x, qa0);
        qa0 = fmaf(qe[5], a01.y, qa0); qa0 = fmaf(qe[6], a01.z, qa0);
        qa0 = fmaf(qe[7], a01.w, qa0);
        float ex0 = __expf((d0 + qa0) * scale);
        den += ex0;
#pragma unroll
        for (int c = 0; c < C; ++c) num[c] = fmaf(ex0, v0[c], num[c]);
        sacc[0] = fmaf(ex0, a00.x, sacc[0]);
        sacc[1] = fmaf(ex0, a00.y, sacc[1]);
        sacc[2] = fmaf(ex0, a00.z, sacc[2]);
        sacc[3] = fmaf(ex0, a00.w, sacc[3]);
        sacc[4] = fmaf(ex0, a01.x, sacc[4]);
        sacc[5] = fmaf(ex0, a01.y, sacc[5]);
        sacc[6] = fmaf(ex0, a01.z, sacc[6]);
        sacc[7] = fmaf(ex0, a01.w, sacc[7]);
    }

    float inv = 1.f / (den + 1e-16f);
    float outc[C], sc[C];
    float gd = 0.f;
#pragma unroll
    for (int c = 0; c < C; ++c) {
        float e_ = 0.f;
#pragma unroll
        for (int d = 0; d < 8; ++d) e_ = fmaf(we[d * HC + h * C + c], sacc[d], e_);
        float o = (num[c] + e_) * inv;
        float s_ = S[(size_t)n * HC + h * C + c];
        outc[c] = o;
        sc[c] = s_;
        gd += o * wb[h * C + c] + s_ * wb[HC + h * C + c] + (o - s_) * wb[2 * HC + h * C + c];
    }
    gd += __shfl_xor(gd, 1, 8);
    gd += __shfl_xor(gd, 2, 8);
    gd += __shfl_xor(gd, 4, 8);
    float g = 1.f / (1.f + __expf(-gd));
#pragma unroll
    for (int c = 0; c < C; ++c) {
        float hh = fmaxf(g * sc[c] + (1.f - g) * outc[c], 0.f);
        OUT[(size_t)n * HC + h * C + c] = hh;
    }
}

// ---- fused gather+gate+classifier, H=1,C=64: 16 lanes/node, factorized ----
template<bool PERM>
__global__ void gather64f_kernel(const int* __restrict__ rowptr,
                                 const int* __restrict__ srcp,
                                 const int2* __restrict__ rec,
                                 const float* __restrict__ eap,
                                 const float* __restrict__ ea,
                                 const float* __restrict__ we,
                                 const float* __restrict__ Q,
                                 const float* __restrict__ K,
                                 const float* __restrict__ V,
                                 const float* __restrict__ S,
                                 const float* __restrict__ wb,
                                 const float* __restrict__ wc,
                                 const float* __restrict__ bc,
                                 float* __restrict__ OUT,
                                 int N, float scale)
{
    int grp = (blockIdx.x * blockDim.x + threadIdx.x) >> 4;   // node
    int l16 = threadIdx.x & 15;
    if (grp >= N) return;
    int c0 = l16 << 2;

    float wv[8][4];
#pragma unroll
    for (int d = 0; d < 8; ++d) *(float4*)wv[d] = *(const float4*)(we + d * 64 + c0);
    float4 qv = *(const float4*)(Q + (size_t)grp * 64 + c0);
    float qe[8];
#pragma unroll
    for (int d = 0; d < 8; ++d) {
        float t = wv[d][0] * qv.x;
        t = fmaf(wv[d][1], qv.y, t);
        t = fmaf(wv[d][2], qv.z, t);
        t = fmaf(wv[d][3], qv.w, t);
        qe[d] = t;
    }

    float num0 = 0.f, num1 = 0.f, num2 = 0.f, num3 = 0.f, den = 0.f;
    float sacc[8];
#pragma unroll
    for (int d = 0; d < 8; ++d) sacc[d] = 0.f;

    int rs = rowptr[grp], re = rowptr[grp + 1];
    int j = rs;
    for (; j + 1 < re; j += 2) {
        int s0, s1;
        const float *A0, *A1;
        if (PERM) {
            s0 = srcp[j]; s1 = srcp[j + 1];
            A0 = eap + (size_t)j * 8; A1 = eap + (size_t)(j + 1) * 8;
        } else {
            int2 r0 = rec[j], r1 = rec[j + 1];
            s0 = r0.x; s1 = r1.x;
            A0 = ea + (size_t)r0.y * 8; A1 = ea + (size_t)r1.y * 8;
        }
        float4 a00 = *(const float4*)A0;
        float4 a01 = *(const float4*)(A0 + 4);
        float4 a10 = *(const float4*)A1;
        float4 a11 = *(const float4*)(A1 + 4);
        float4 k0 = *(const float4*)(K + (size_t)s0 * 64 + c0);
        float4 v0 = *(const float4*)(V + (size_t)s0 * 64 + c0);
        float4 k1 = *(const float4*)(K + (size_t)s1 * 64 + c0);
        float4 v1 = *(const float4*)(V + (size_t)s1 * 64 + c0);
        float t0 = qv.x * k0.x;
        t0 = fmaf(qv.y, k0.y, t0); t0 = fmaf(qv.z, k0.z, t0); t0 = fmaf(qv.w, k0.w, t0);
        t0 = fmaf(qe[0], a00.x, t0); t0 = fmaf(qe[1], a00.y, t0);
        t0 = fmaf(qe[2], a00.z, t0); t0 = fmaf(qe[3], a00.w, t0);
        t0 = fmaf(qe[4], a01.x, t0); t0 = fmaf(qe[5], a01.y, t0);
        t0 = fmaf(qe[6], a01.z, t0); t0 = fmaf(qe[7], a01.w, t0);
        float t1 = qv.x * k1.x;
        t1 = fmaf(qv.y, k1.y, t1); t1 = fmaf(qv.z, k1.z, t1); t1 = fmaf(qv.w, k1.w, t1);
        t1 = fmaf(qe[0], a10.x, t1); t1 = fmaf(qe[1], a10.y, t1);
        t1 = fmaf(qe[2], a10.z, t1); t1 = fmaf(qe[3], a10.w, t1);
        t1 = fmaf(qe[4], a11.x, t1); t1 = fmaf(qe[5], a11.y, t1);
        t1 = fmaf(qe[6], a11.z, t1); t1 = fmaf(qe[7], a11.w, t1);
#pragma unroll
        for (int off = 8; off > 0; off >>= 1) {
            t0 += __shfl_xor(t0, off, 16);
            t1 += __shfl_xor(t1, off, 16);
        }
        float ex0 = __expf(t0 * scale);
        float ex1 = __expf(t1 * scale);
        den += ex0 + ex1;
        num0 = fmaf(ex0, v0.x, fmaf(ex1, v1.x, num0));
        num1 = fmaf(ex0, v0.y, fmaf(ex1, v1.y, num1));
        num2 = fmaf(ex0, v0.z, fmaf(ex1, v1.z, num2));
        num3 = fmaf(ex0, v0.w, fmaf(ex1, v1.w, num3));
        sacc[0] = fmaf(ex0, a00.x, fmaf(ex1, a10.x, sacc[0]));
        sacc[1] = fmaf(ex0, a00.y, fmaf(ex1, a10.y, sacc[1]));
        sacc[2] = fmaf(ex0, a00.z, fmaf(ex1, a10.z, sacc[2]));
        sacc[3] = fmaf(ex0, a00.w, fmaf(ex1, a10.w, sacc[3]));
        sacc[4] = fmaf(ex0, a01.x, fmaf(ex1, a11.x, sacc[4]));
        sacc[5] = fmaf(ex0, a01.y, fmaf(ex1, a11.y, sacc[5]));
        sacc[6] = fmaf(ex0, a01.z, fmaf(ex1, a11.z, sacc[6]));
        sacc[7] = fmaf(ex0, a01.w, fmaf(ex1, a11.w, sacc[7]));
    }
    if (j < re) {
        int s0;
        const float* A0;
        if (PERM) {
            s0 = srcp[j];
            A0 = eap + (size_t)j * 8;
        } else {
            int2 r0 = rec[j];
            s0 = r0.x;
            A0 = ea + (size_t)r0.y * 8;
        }
        float4 a00 = *(const float4*)A0;
        float4 a01 = *(const float4*)(A0 + 4);
        float4 k0 = *(const float4*)(K + (size_t)s0 * 64 + c0);
        float4 v0 = *(const float4*)(V + (size_t)s0 * 64 + c0);
        float t0 = qv.x * k0.x;
        t0 = fmaf(qv.y, k0.y, t0); t0 = fmaf(qv.z, k0.z, t0); t0 = fmaf(qv.w, k0.w, t0);
        t0 = fmaf(qe[0], a00.x, t0); t0 = fmaf(qe[1], a00.y, t0);
        t0 = fmaf(qe[2], a00.z, t0); t0 = fmaf(qe[3], a00.w, t0);
        t0 = fmaf(qe[4], a01.x, t0); t0 = fmaf(qe[5], a01.y, t0);
        t0 = fmaf(qe[6], a01.z, t0); t0 = fmaf(qe[7], a01.w, t0);
#pragma unroll
        for (int off = 8; off > 0; off >>= 1) t0 += __shfl_xor(t0, off, 16);
        float ex0 = __expf(t0 * scale);
        den += ex0;
        num0 = fmaf(ex0, v0.x, num0);
        num1 = fmaf(ex0, v0.y, num1);
        num2 = fmaf(ex0, v0.z, num2);
        num3 = fmaf(ex0, v0.w, num3);
        sacc[0] = fmaf(ex0, a00.x, sacc[0]);
        sacc[1] = fmaf(ex0, a00.y, sacc[1]);
        sacc[2] = fmaf(ex0, a00.z, sacc[2]);
        sacc[3] = fmaf(ex0, a00.w, sacc[3]);
        sacc[4] = fmaf(ex0, a01.x, sacc[4]);
        sacc[5] = fmaf(ex0, a01.y, sacc[5]);
        sacc[6] = fmaf(ex0, a01.z, sacc[6]);
        sacc[7] = fmaf(ex0, a01.w, sacc[7]);
    }

#pragma unroll
    for (int d = 0; d < 8; ++d) {
        num0 = fmaf(wv[d][0], sacc[d], num0);
        num1 = fmaf(wv[d][1], sacc[d], num1);
        num2 = fmaf(wv[d][2], sacc[d], num2);
        num3 = fmaf(wv[d][3], sacc[d], num3);
    }
    float inv = 1.f / (den + 1e-16f);
    float o0 = num0 * inv, o1 = num1 * inv, o2 = num2 * inv, o3 = num3 * inv;
    float4 sv  = *(const float4*)(S + (size_t)grp * 64 + c0);
    float4 wb0 = *(const float4*)(wb + c0);
    float4 wb1 = *(const float4*)(wb + 64 + c0);
    float4 wb2 = *(const float4*)(wb + 128 + c0);
    float gd = o0 * wb0.x + sv.x * wb1.x + (o0 - sv.x) * wb2.x;
    gd += o1 * wb0.y + sv.y * wb1.y + (o1 - sv.y) * wb2.y;
    gd += o2 * wb0.z + sv.z * wb1.z + (o2 - sv.z) * wb2.z;
    gd += o3 * wb0.w + sv.w * wb1.w + (o3 - sv.w) * wb2.w;
#pragma unroll
    for (int off = 8; off > 0; off >>= 1) gd += __shfl_xor(gd, off, 16);
    float g = 1.f / (1.f + __expf(-gd));
    float h0 = fmaxf(g * sv.x + (1.f - g) * o0, 0.f);
    float h1 = fmaxf(g * sv.y + (1.f - g) * o1, 0.f);
    float h2 = fmaxf(g * sv.z + (1.f - g) * o2, 0.f);
    float h3 = fmaxf(g * sv.w + (1.f - g) * o3, 0.f);
    float4 wcv = *(const float4*)(wc + c0);
    float t = h0 * wcv.x + h1 * wcv.y + h2 * wcv.z + h3 * wcv.w;
#pragma unroll
    for (int off = 8; off > 0; off >>= 1) t += __shfl_xor(t, off, 16);
    if (l16 == 0) OUT[grp] = t + bc[0];
}

extern "C" void kernel_launch(void* const* d_in, const int* in_sizes, int n_in,
                              void* d_out, int out_size, void* d_ws, size_t ws_size,
                              hipStream_t stream) {
    const float* x  = (const float*)d_in[0];
    const int*   ei = (const int*)d_in[1];
    const float* ea = (const float*)d_in[2];
    const int N = in_sizes[0] / 32;
    const int E = in_sizes[1] / 2;

    int p = 3;
    const float *wq1=(const float*)d_in[p+0], *bq1=(const float*)d_in[p+1],
                *wk1=(const float*)d_in[p+2], *bk1=(const float*)d_in[p+3],
                *wv1=(const float*)d_in[p+4], *bv1=(const float*)d_in[p+5],
                *we1=(const float*)d_in[p+6],
                *wsk1=(const float*)d_in[p+7], *bsk1=(const float*)d_in[p+8],
                *wb1=(const float*)d_in[p+9];
    p += 10;
    const float *wq2=(const float*)d_in[p+0], *bq2=(const float*)d_in[p+1],
                *wk2=(const float*)d_in[p+2], *bk2=(const float*)d_in[p+3],
                *wv2=(const float*)d_in[p+4], *bv2=(const float*)d_in[p+5],
                *we2=(const float*)d_in[p+6],
                *wsk2=(const float*)d_in[p+7], *bsk2=(const float*)d_in[p+8],
                *wb2=(const float*)d_in[p+9];
    p += 10;
    const float *wq3=(const float*)d_in[p+0], *bq3=(const float*)d_in[p+1],
                *wk3=(const float*)d_in[p+2], *bk3=(const float*)d_in[p+3],
                *wv3=(const float*)d_in[p+4], *bv3=(const float*)d_in[p+5],
                *we3=(const float*)d_in[p+6],
                *wsk3=(const float*)d_in[p+7], *bsk3=(const float*)d_in[p+8],
                *wb3=(const float*)d_in[p+9];
    p += 10;
    const float *wc = (const float*)d_in[p+0], *bc = (const float*)d_in[p+1];

    float* out = (float*)d_out;

    // ---- workspace layout ----
    size_t NB = (size_t)N * 64;
    float* ws = (float*)d_ws;
    float* Hb = ws;              // N*48 (max hidden between layers)
    float* Qb = Hb + (size_t)N * 48;
    float* Kb = Qb + NB;
    float* Vb = Kb + NB;
    float* Sb = Vb + NB;
    int* ip      = (int*)(Sb + NB);
    int* rowptr  = ip;                 // N+2
    int* deg     = rowptr + (N + 2);   // N (cursor)
    int* bsum    = deg + N;            // 512
    int* boff    = bsum + 512;         // 512
    int* idx_end = boff + 512;

    // PERM layout: srcp[E] then 16B-aligned eap[E*8]
    int* srcp = idx_end;
    size_t eap_off = (size_t)((char*)(srcp + E) - (char*)d_ws);
    eap_off = (eap_off + 15) & ~(size_t)15;
    float* eap = (float*)((char*)d_ws + eap_off);
    size_t need_perm = eap_off + (size_t)E * 8 * sizeof(float);

    // fallback layout: rec[E] (int2)
    size_t rec_off = (size_t)((char*)idx_end - (char*)d_ws);
    rec_off = (rec_off + 7) & ~(size_t)7;
    int2* rec = (int2*)((char*)d_ws + rec_off);

    const bool PERM = (ws_size >= need_perm);

    const int BLK = 256;
    const int NBLK = (N + SCAN_BLK - 1) / SCAN_BLK;

    // ---------------- CSR build ----------------
    hipMemsetAsync(deg, 0, (size_t)N * sizeof(int), stream);
    count_kernel<<<(E + BLK - 1) / BLK, BLK, 0, stream>>>(ei, deg, E);
    scan1_kernel<<<NBLK, SCAN_BLK, 0, stream>>>(deg, rowptr, bsum, N);
    scan2_kernel<<<1, 512, 0, stream>>>(bsum, boff, NBLK);
    scan3_kernel<<<(N + BLK - 1) / BLK, BLK, 0, stream>>>(rowptr, boff, N, E);
    hipMemsetAsync(deg, 0, (size_t)N * sizeof(int), stream);
    if (PERM) {
        scatterE_kernel<<<(E + BLK - 1) / BLK, BLK, 0, stream>>>(ei, rowptr, deg, srcp, E);
        permuteE_kernel<<<(E + BLK - 1) / BLK, BLK, 0, stream>>>(ei, ea, srcp, eap, E);
    } else {
        scatterR_kernel<<<(E + BLK - 1) / BLK, BLK, 0, stream>>>(ei, rowptr, deg, rec, E);
    }

    // ------- layer 1: cin=32, H=8, C=6 (pad 8) -------
    proj_kernel<32,8,6,8><<<(N*48 + BLK-1)/BLK, BLK, 0, stream>>>(
        x, wq1,bq1, wk1,bk1, wv1,bv1, wsk1,bsk1, Qb,Kb,Vb,Sb, N);
    if (PERM)
        gather8f_kernel<6,8,true><<<(N*8 + BLK-1)/BLK, BLK, 0, stream>>>(
            rowptr, srcp, rec, eap, ea, we1, Qb, Kb, Vb, Sb, wb1, Hb, N, 1.0f/sqrtf(6.0f));
    else
        gather8f_kernel<6,8,false><<<(N*8 + BLK-1)/BLK, BLK, 0, stream>>>(
            rowptr, srcp, rec, eap, ea, we1, Qb, Kb, Vb, Sb, wb1, Hb, N, 1.0f/sqrtf(6.0f));

    // ------- layer 2: cin=48, H=8, C=3 (pad 4) -------
    proj_kernel<48,8,3,4><<<(N*24 + BLK-1)/BLK, BLK, 0, stream>>>(
        Hb, wq2,bq2, wk2,bk2, wv2,bv2, wsk2,bsk2, Qb,Kb,Vb,Sb, N);
    if (PERM)
        gather8f_kernel<3,4,true><<<(N*8 + BLK-1)/BLK, BLK, 0, stream>>>(
            rowptr, srcp, rec, eap, ea, we2, Qb, Kb, Vb, Sb, wb2, Hb, N, 1.0f/sqrtf(3.0f));
    else
        gather8f_kernel<3,4,false><<<(N*8 + BLK-1)/BLK, BLK, 0, stream>>>(
            rowptr, srcp, rec, eap, ea, we2, Qb, Kb, Vb, Sb, wb2, Hb, N, 1.0f/sqrtf(3.0f));

    // ------- layer 3: cin=24, H=1, C=64 -------
    proj_kernel<24,1,64,64><<<(N*64 + BLK-1)/BLK, BLK, 0, stream>>>(
        Hb, wq3,bq3, wk3,bk3, wv3,bv3, wsk3,bsk3, Qb,Kb,Vb,Sb, N);
    if (PERM)
        gather64f_kernel<true><<<((size_t)N*16 + BLK-1)/BLK, BLK, 0, stream>>>(
            rowptr, srcp, rec, eap, ea, we3, Qb, Kb, Vb, Sb, wb3, wc, bc, out, N, 1.0f/8.0f);
    else
        gather64f_kernel<false><<<((size_t)N*16 + BLK-1)/BLK, BLK, 0, stream>>>(
            rowptr, srcp, rec, eap, ea, we3, Qb, Kb, Vb, Sb, wb3, wc, bc, out, N, 1.0f/8.0f);
}

// Round 7
// 1127.988 us; speedup vs baseline: 1.2392x; 1.2392x over previous
//
#include <hip/hip_runtime.h>
#include <hip/hip_fp16.h>
#include <math.h>

#define SCAN_BLK 256

__device__ __forceinline__ float2 H2F(unsigned u) {
    __half2 h = *reinterpret_cast<__half2*>(&u);
    return __half22float2(h);
}
__device__ __forceinline__ unsigned F2H(float a, float b) {
    __half2 h = __floats2half2_rn(a, b);
    return *reinterpret_cast<unsigned*>(&h);
}

// unpack 8 fp16 edge attrs
__device__ __forceinline__ void loadA(const __half* p, float* a) {
    uint4 u = *(const uint4*)p;
    float2 t;
    t = H2F(u.x); a[0] = t.x; a[1] = t.y;
    t = H2F(u.y); a[2] = t.x; a[3] = t.y;
    t = H2F(u.z); a[4] = t.x; a[5] = t.y;
    t = H2F(u.w); a[6] = t.x; a[7] = t.y;
}

// packed per-head K/V fp16 packet: [k0..kC-1, v0..vC-1, pad...] (PK halfs)
template<int C>
__device__ __forceinline__ void loadKV(const __half* p, float* k, float* v) {
    if constexpr (C == 6) {
        uint4 p0 = *(const uint4*)p;
        uint4 p1 = *(const uint4*)(p + 8);
        float2 t;
        t = H2F(p0.x); k[0] = t.x; k[1] = t.y;
        t = H2F(p0.y); k[2] = t.x; k[3] = t.y;
        t = H2F(p0.z); k[4] = t.x; k[5] = t.y;
        t = H2F(p0.w); v[0] = t.x; v[1] = t.y;
        t = H2F(p1.x); v[2] = t.x; v[3] = t.y;
        t = H2F(p1.y); v[4] = t.x; v[5] = t.y;
    } else {  // C == 3: [k0,k1,k2,v0,v1,v2,p,p]
        uint4 p0 = *(const uint4*)p;
        float2 t;
        t = H2F(p0.x); k[0] = t.x; k[1] = t.y;
        t = H2F(p0.y); k[2] = t.x; v[0] = t.y;
        t = H2F(p0.z); v[1] = t.x; v[2] = t.y;
    }
}

// ---------------- ea -> fp16 (sequential) ----------------
__global__ void cvt_ea_kernel(const float* __restrict__ ea, __half* __restrict__ ea16, int E) {
    int e = blockIdx.x * blockDim.x + threadIdx.x;
    if (e >= E) return;
    float4 a0 = *(const float4*)(ea + (size_t)e * 8);
    float4 a1 = *(const float4*)(ea + (size_t)e * 8 + 4);
    uint4 u;
    u.x = F2H(a0.x, a0.y);
    u.y = F2H(a0.z, a0.w);
    u.z = F2H(a1.x, a1.y);
    u.w = F2H(a1.z, a1.w);
    *(uint4*)(ea16 + (size_t)e * 8) = u;
}

// ---------------- CSR build ----------------
__global__ void count_kernel(const int* __restrict__ ei, int* __restrict__ deg, int E) {
    int e = blockIdx.x * blockDim.x + threadIdx.x;
    if (e < E) atomicAdd(&deg[ei[E + e]], 1);
}

__global__ void scan1_kernel(const int* __restrict__ deg, int* __restrict__ part,
                             int* __restrict__ bsum, int N) {
    __shared__ int sm[SCAN_BLK];
    int i = blockIdx.x * SCAN_BLK + threadIdx.x;
    int v = (i < N) ? deg[i] : 0;
    sm[threadIdx.x] = v;
    __syncthreads();
    for (int off = 1; off < SCAN_BLK; off <<= 1) {
        int t = (threadIdx.x >= off) ? sm[threadIdx.x - off] : 0;
        __syncthreads();
        sm[threadIdx.x] += t;
        __syncthreads();
    }
    if (i < N) part[i] = sm[threadIdx.x] - v;
    if (threadIdx.x == SCAN_BLK - 1) bsum[blockIdx.x] = sm[threadIdx.x];
}

__global__ void scan2_kernel(const int* __restrict__ bsum, int* __restrict__ boff, int nb) {
    __shared__ int sm[512];
    int v = (threadIdx.x < nb) ? bsum[threadIdx.x] : 0;
    sm[threadIdx.x] = v;
    __syncthreads();
    for (int off = 1; off < 512; off <<= 1) {
        int t = (threadIdx.x >= off) ? sm[threadIdx.x - off] : 0;
        __syncthreads();
        sm[threadIdx.x] += t;
        __syncthreads();
    }
    if (threadIdx.x < nb) boff[threadIdx.x] = sm[threadIdx.x] - v;
}

__global__ void scan3_kernel(int* __restrict__ rowptr, const int* __restrict__ boff,
                             int N, int E) {
    int i = blockIdx.x * blockDim.x + threadIdx.x;
    if (i < N) rowptr[i] += boff[i / SCAN_BLK];
    if (i == 0) rowptr[N] = E;
}

// scatter the 4B edge id into CSR slot
__global__ void scatterE_kernel(const int* __restrict__ ei, const int* __restrict__ rowptr,
                                int* __restrict__ cursor, int* __restrict__ srcp, int E) {
    int e = blockIdx.x * blockDim.x + threadIdx.x;
    if (e >= E) return;
    int dst = ei[E + e];
    int pos = atomicAdd(&cursor[dst], 1);
    srcp[rowptr[dst] + pos] = e;       // temporarily holds eid
}

// gather-permute: coalesced writes; random 16B ea16 reads; srcp: eid -> src
__global__ void permuteE_kernel(const int* __restrict__ ei, const __half* __restrict__ ea16,
                                int* __restrict__ srcp, __half* __restrict__ eap, int E) {
    int j = blockIdx.x * blockDim.x + threadIdx.x;
    if (j >= E) return;
    int e = srcp[j];
    uint4 a = *(const uint4*)(ea16 + (size_t)e * 8);
    *(uint4*)(eap + (size_t)j * 8) = a;
    srcp[j] = ei[e];
}

// ------- projections, H=8 layers: Q,S fp32 unpadded; KV fp16 packed -------
template<int CIN, int C, int PK>
__global__ void proj8_kernel(const float* __restrict__ X,
                             const float* __restrict__ wq, const float* __restrict__ bq,
                             const float* __restrict__ wk, const float* __restrict__ bk,
                             const float* __restrict__ wv, const float* __restrict__ bv,
                             const float* __restrict__ wsk, const float* __restrict__ bsk,
                             float* __restrict__ Q, __half* __restrict__ KV,
                             float* __restrict__ S, int N)
{
    const int HC = 8 * C;
    int idx = blockIdx.x * blockDim.x + threadIdx.x;
    if (idx >= N * HC) return;
    int n = idx / HC;
    int c = idx - n * HC;
    int h = c / C;
    int cc = c - h * C;
    float q = bq[c], k = bk[c], v = bv[c], s = bsk[c];
    const float* xr = X + (size_t)n * CIN;
#pragma unroll
    for (int i = 0; i < CIN; ++i) {
        float xi = xr[i];
        q = fmaf(xi, wq[i * HC + c], q);
        k = fmaf(xi, wk[i * HC + c], k);
        v = fmaf(xi, wv[i * HC + c], v);
        s = fmaf(xi, wsk[i * HC + c], s);
    }
    Q[(size_t)n * HC + c] = q;
    __half* kp = KV + (size_t)n * (8 * PK) + h * PK;
    kp[cc] = __float2half_rn(k);
    kp[C + cc] = __float2half_rn(v);
    S[(size_t)n * HC + c] = s;
}

// ------- projection, layer3: Q,S fp32; K,V fp16 rows of 64 -------
__global__ void proj64_kernel(const float* __restrict__ X,
                              const float* __restrict__ wq, const float* __restrict__ bq,
                              const float* __restrict__ wk, const float* __restrict__ bk,
                              const float* __restrict__ wv, const float* __restrict__ bv,
                              const float* __restrict__ wsk, const float* __restrict__ bsk,
                              float* __restrict__ Q, __half* __restrict__ K16,
                              __half* __restrict__ V16, float* __restrict__ S, int N)
{
    int idx = blockIdx.x * blockDim.x + threadIdx.x;
    if (idx >= N * 64) return;
    int n = idx >> 6;
    int c = idx & 63;
    float q = bq[c], k = bk[c], v = bv[c], s = bsk[c];
    const float* xr = X + (size_t)n * 24;
#pragma unroll
    for (int i = 0; i < 24; ++i) {
        float xi = xr[i];
        q = fmaf(xi, wq[i * 64 + c], q);
        k = fmaf(xi, wk[i * 64 + c], k);
        v = fmaf(xi, wv[i * 64 + c], v);
        s = fmaf(xi, wsk[i * 64 + c], s);
    }
    Q[idx] = q;
    K16[idx] = __float2half_rn(k);
    V16[idx] = __float2half_rn(v);
    S[idx] = s;
}

// ---- fused gather+gate, H=8: thread per (node, head), factorized e -----
template<int C, int PK>
__global__ void gather8f_kernel(const int* __restrict__ rowptr,
                                const int* __restrict__ srcp,
                                const __half* __restrict__ eap,
                                const float* __restrict__ we,
                                const float* __restrict__ Q,
                                const __half* __restrict__ KV,
                                const float* __restrict__ S,
                                const float* __restrict__ wb,
                                float* __restrict__ OUT,
                                int N, float scale)
{
    const int HC = 8 * C;
    int tid = blockIdx.x * blockDim.x + threadIdx.x;
    int n = tid >> 3;
    int h = tid & 7;
    if (n >= N) return;

    float q[C];
    const float* Qp = Q + (size_t)n * HC + h * C;
#pragma unroll
    for (int c = 0; c < C; ++c) q[c] = Qp[c];

    float qe[8];
#pragma unroll
    for (int d = 0; d < 8; ++d) {
        float t = 0.f;
#pragma unroll
        for (int c = 0; c < C; ++c) t = fmaf(we[d * HC + h * C + c], q[c], t);
        qe[d] = t;
    }

    float num[C];
#pragma unroll
    for (int c = 0; c < C; ++c) num[c] = 0.f;
    float sacc[8];
#pragma unroll
    for (int d = 0; d < 8; ++d) sacc[d] = 0.f;
    float den = 0.f;

    int rs = rowptr[n], re = rowptr[n + 1];
    int j = rs;
    for (; j + 1 < re; j += 2) {
        int s0 = srcp[j], s1 = srcp[j + 1];
        float a0[8], a1[8];
        loadA(eap + (size_t)j * 8, a0);
        loadA(eap + (size_t)(j + 1) * 8, a1);
        float k0[C], v0[C], k1[C], v1[C];
        loadKV<C>(KV + (size_t)s0 * (8 * PK) + h * PK, k0, v0);
        loadKV<C>(KV + (size_t)s1 * (8 * PK) + h * PK, k1, v1);
        float d0 = 0.f, d1 = 0.f;
#pragma unroll
        for (int c = 0; c < C; ++c) {
            d0 = fmaf(q[c], k0[c], d0);
            d1 = fmaf(q[c], k1[c], d1);
        }
        float qa0 = 0.f, qa1 = 0.f;
#pragma unroll
        for (int d = 0; d < 8; ++d) {
            qa0 = fmaf(qe[d], a0[d], qa0);
            qa1 = fmaf(qe[d], a1[d], qa1);
        }
        float ex0 = __expf((d0 + qa0) * scale);
        float ex1 = __expf((d1 + qa1) * scale);
        den += ex0 + ex1;
#pragma unroll
        for (int c = 0; c < C; ++c) {
            num[c] = fmaf(ex0, v0[c], num[c]);
            num[c] = fmaf(ex1, v1[c], num[c]);
        }
#pragma unroll
        for (int d = 0; d < 8; ++d)
            sacc[d] = fmaf(ex0, a0[d], fmaf(ex1, a1[d], sacc[d]));
    }
    if (j < re) {
        int s0 = srcp[j];
        float a0[8];
        loadA(eap + (size_t)j * 8, a0);
        float k0[C], v0[C];
        loadKV<C>(KV + (size_t)s0 * (8 * PK) + h * PK, k0, v0);
        float d0 = 0.f;
#pragma unroll
        for (int c = 0; c < C; ++c) d0 = fmaf(q[c], k0[c], d0);
        float qa0 = 0.f;
#pragma unroll
        for (int d = 0; d < 8; ++d) qa0 = fmaf(qe[d], a0[d], qa0);
        float ex0 = __expf((d0 + qa0) * scale);
        den += ex0;
#pragma unroll
        for (int c = 0; c < C; ++c) num[c] = fmaf(ex0, v0[c], num[c]);
#pragma unroll
        for (int d = 0; d < 8; ++d) sacc[d] = fmaf(ex0, a0[d], sacc[d]);
    }

    float inv = 1.f / (den + 1e-16f);
    float outc[C], sc[C];
    float gd = 0.f;
#pragma unroll
    for (int c = 0; c < C; ++c) {
        float e_ = 0.f;
#pragma unroll
        for (int d = 0; d < 8; ++d) e_ = fmaf(we[d * HC + h * C + c], sacc[d], e_);
        float o = (num[c] + e_) * inv;
        float s_ = S[(size_t)n * HC + h * C + c];
        outc[c] = o;
        sc[c] = s_;
        gd += o * wb[h * C + c] + s_ * wb[HC + h * C + c] + (o - s_) * wb[2 * HC + h * C + c];
    }
    gd += __shfl_xor(gd, 1, 8);
    gd += __shfl_xor(gd, 2, 8);
    gd += __shfl_xor(gd, 4, 8);
    float g = 1.f / (1.f + __expf(-gd));
#pragma unroll
    for (int c = 0; c < C; ++c) {
        float hh = fmaxf(g * sc[c] + (1.f - g) * outc[c], 0.f);
        OUT[(size_t)n * HC + h * C + c] = hh;
    }
}

// ---- fused gather+gate+classifier, H=1,C=64: 16 lanes/node, factorized ----
__global__ void gather64f_kernel(const int* __restrict__ rowptr,
                                 const int* __restrict__ srcp,
                                 const __half* __restrict__ eap,
                                 const float* __restrict__ we,
                                 const float* __restrict__ Q,
                                 const __half* __restrict__ K16,
                                 const __half* __restrict__ V16,
                                 const float* __restrict__ S,
                                 const float* __restrict__ wb,
                                 const float* __restrict__ wc,
                                 const float* __restrict__ bc,
                                 float* __restrict__ OUT,
                                 int N, float scale)
{
    int grp = (blockIdx.x * blockDim.x + threadIdx.x) >> 4;   // node
    int l16 = threadIdx.x & 15;
    if (grp >= N) return;
    int c0 = l16 << 2;

    float wv[8][4];
#pragma unroll
    for (int d = 0; d < 8; ++d) *(float4*)wv[d] = *(const float4*)(we + d * 64 + c0);
    float4 qv = *(const float4*)(Q + (size_t)grp * 64 + c0);
    float qe[8];
#pragma unroll
    for (int d = 0; d < 8; ++d) {
        float t = wv[d][0] * qv.x;
        t = fmaf(wv[d][1], qv.y, t);
        t = fmaf(wv[d][2], qv.z, t);
        t = fmaf(wv[d][3], qv.w, t);
        qe[d] = t;
    }

    float num0 = 0.f, num1 = 0.f, num2 = 0.f, num3 = 0.f, den = 0.f;
    float sacc[8];
#pragma unroll
    for (int d = 0; d < 8; ++d) sacc[d] = 0.f;

    int rs = rowptr[grp], re = rowptr[grp + 1];
    int j = rs;
    for (; j + 1 < re; j += 2) {
        int s0 = srcp[j], s1 = srcp[j + 1];
        float a0[8], a1[8];
        loadA(eap + (size_t)j * 8, a0);
        loadA(eap + (size_t)(j + 1) * 8, a1);
        uint2 ku0 = *(const uint2*)(K16 + (size_t)s0 * 64 + c0);
        uint2 vu0 = *(const uint2*)(V16 + (size_t)s0 * 64 + c0);
        uint2 ku1 = *(const uint2*)(K16 + (size_t)s1 * 64 + c0);
        uint2 vu1 = *(const uint2*)(V16 + (size_t)s1 * 64 + c0);
        float2 ka0 = H2F(ku0.x), kb0 = H2F(ku0.y);
        float2 va0 = H2F(vu0.x), vb0 = H2F(vu0.y);
        float2 ka1 = H2F(ku1.x), kb1 = H2F(ku1.y);
        float2 va1 = H2F(vu1.x), vb1 = H2F(vu1.y);
        float t0 = qv.x * ka0.x;
        t0 = fmaf(qv.y, ka0.y, t0); t0 = fmaf(qv.z, kb0.x, t0); t0 = fmaf(qv.w, kb0.y, t0);
        float t1 = qv.x * ka1.x;
        t1 = fmaf(qv.y, ka1.y, t1); t1 = fmaf(qv.z, kb1.x, t1); t1 = fmaf(qv.w, kb1.y, t1);
#pragma unroll
        for (int d = 0; d < 8; ++d) {
            t0 = fmaf(qe[d], a0[d], t0);
            t1 = fmaf(qe[d], a1[d], t1);
        }
#pragma unroll
        for (int off = 8; off > 0; off >>= 1) {
            t0 += __shfl_xor(t0, off, 16);
            t1 += __shfl_xor(t1, off, 16);
        }
        float ex0 = __expf(t0 * scale);
        float ex1 = __expf(t1 * scale);
        den += ex0 + ex1;
        num0 = fmaf(ex0, va0.x, fmaf(ex1, va1.x, num0));
        num1 = fmaf(ex0, va0.y, fmaf(ex1, va1.y, num1));
        num2 = fmaf(ex0, vb0.x, fmaf(ex1, vb1.x, num2));
        num3 = fmaf(ex0, vb0.y, fmaf(ex1, vb1.y, num3));
#pragma unroll
        for (int d = 0; d < 8; ++d)
            sacc[d] = fmaf(ex0, a0[d], fmaf(ex1, a1[d], sacc[d]));
    }
    if (j < re) {
        int s0 = srcp[j];
        float a0[8];
        loadA(eap + (size_t)j * 8, a0);
        uint2 ku0 = *(const uint2*)(K16 + (size_t)s0 * 64 + c0);
        uint2 vu0 = *(const uint2*)(V16 + (size_t)s0 * 64 + c0);
        float2 ka0 = H2F(ku0.x), kb0 = H2F(ku0.y);
        float2 va0 = H2F(vu0.x), vb0 = H2F(vu0.y);
        float t0 = qv.x * ka0.x;
        t0 = fmaf(qv.y, ka0.y, t0); t0 = fmaf(qv.z, kb0.x, t0); t0 = fmaf(qv.w, kb0.y, t0);
#pragma unroll
        for (int d = 0; d < 8; ++d) t0 = fmaf(qe[d], a0[d], t0);
#pragma unroll
        for (int off = 8; off > 0; off >>= 1) t0 += __shfl_xor(t0, off, 16);
        float ex0 = __expf(t0 * scale);
        den += ex0;
        num0 = fmaf(ex0, va0.x, num0);
        num1 = fmaf(ex0, va0.y, num1);
        num2 = fmaf(ex0, vb0.x, num2);
        num3 = fmaf(ex0, vb0.y, num3);
#pragma unroll
        for (int d = 0; d < 8; ++d) sacc[d] = fmaf(ex0, a0[d], sacc[d]);
    }

#pragma unroll
    for (int d = 0; d < 8; ++d) {
        num0 = fmaf(wv[d][0], sacc[d], num0);
        num1 = fmaf(wv[d][1], sacc[d], num1);
        num2 = fmaf(wv[d][2], sacc[d], num2);
        num3 = fmaf(wv[d][3], sacc[d], num3);
    }
    float inv = 1.f / (den + 1e-16f);
    float o0 = num0 * inv, o1 = num1 * inv, o2 = num2 * inv, o3 = num3 * inv;
    float4 sv  = *(const float4*)(S + (size_t)grp * 64 + c0);
    float4 wb0 = *(const float4*)(wb + c0);
    float4 wb1 = *(const float4*)(wb + 64 + c0);
    float4 wb2 = *(const float4*)(wb + 128 + c0);
    float gd = o0 * wb0.x + sv.x * wb1.x + (o0 - sv.x) * wb2.x;
    gd += o1 * wb0.y + sv.y * wb1.y + (o1 - sv.y) * wb2.y;
    gd += o2 * wb0.z + sv.z * wb1.z + (o2 - sv.z) * wb2.z;
    gd += o3 * wb0.w + sv.w * wb1.w + (o3 - sv.w) * wb2.w;
#pragma unroll
    for (int off = 8; off > 0; off >>= 1) gd += __shfl_xor(gd, off, 16);
    float g = 1.f / (1.f + __expf(-gd));
    float h0 = fmaxf(g * sv.x + (1.f - g) * o0, 0.f);
    float h1 = fmaxf(g * sv.y + (1.f - g) * o1, 0.f);
    float h2 = fmaxf(g * sv.z + (1.f - g) * o2, 0.f);
    float h3 = fmaxf(g * sv.w + (1.f - g) * o3, 0.f);
    float4 wcv = *(const float4*)(wc + c0);
    float t = h0 * wcv.x + h1 * wcv.y + h2 * wcv.z + h3 * wcv.w;
#pragma unroll
    for (int off = 8; off > 0; off >>= 1) t += __shfl_xor(t, off, 16);
    if (l16 == 0) OUT[grp] = t + bc[0];
}

extern "C" void kernel_launch(void* const* d_in, const int* in_sizes, int n_in,
                              void* d_out, int out_size, void* d_ws, size_t ws_size,
                              hipStream_t stream) {
    const float* x  = (const float*)d_in[0];
    const int*   ei = (const int*)d_in[1];
    const float* ea = (const float*)d_in[2];
    const int N = in_sizes[0] / 32;
    const int E = in_sizes[1] / 2;

    int p = 3;
    const float *wq1=(const float*)d_in[p+0], *bq1=(const float*)d_in[p+1],
                *wk1=(const float*)d_in[p+2], *bk1=(const float*)d_in[p+3],
                *wv1=(const float*)d_in[p+4], *bv1=(const float*)d_in[p+5],
                *we1=(const float*)d_in[p+6],
                *wsk1=(const float*)d_in[p+7], *bsk1=(const float*)d_in[p+8],
                *wb1=(const float*)d_in[p+9];
    p += 10;
    const float *wq2=(const float*)d_in[p+0], *bq2=(const float*)d_in[p+1],
                *wk2=(const float*)d_in[p+2], *bk2=(const float*)d_in[p+3],
                *wv2=(const float*)d_in[p+4], *bv2=(const float*)d_in[p+5],
                *we2=(const float*)d_in[p+6],
                *wsk2=(const float*)d_in[p+7], *bsk2=(const float*)d_in[p+8],
                *wb2=(const float*)d_in[p+9];
    p += 10;
    const float *wq3=(const float*)d_in[p+0], *bq3=(const float*)d_in[p+1],
                *wk3=(const float*)d_in[p+2], *bk3=(const float*)d_in[p+3],
                *wv3=(const float*)d_in[p+4], *bv3=(const float*)d_in[p+5],
                *we3=(const float*)d_in[p+6],
                *wsk3=(const float*)d_in[p+7], *bsk3=(const float*)d_in[p+8],
                *wb3=(const float*)d_in[p+9];
    p += 10;
    const float *wc = (const float*)d_in[p+0], *bc = (const float*)d_in[p+1];

    float* out = (float*)d_out;

    // ---- workspace layout ----
    float* ws = (float*)d_ws;
    float* Hb = ws;                               // N*48 fp32
    float* Qb = Hb + (size_t)N * 48;              // N*64 fp32
    float* Sb = Qb + (size_t)N * 64;              // N*64 fp32
    __half* KV16  = (__half*)(Sb + (size_t)N * 64);  // N*128 halfs
    __half* K3    = KV16;                          // layer3 K: N*64
    __half* V3    = KV16 + (size_t)N * 64;         // layer3 V: N*64
    __half* ea16  = KV16 + (size_t)N * 128;        // E*8 halfs
    __half* eap16 = ea16 + (size_t)E * 8;          // E*8 halfs
    int* ip      = (int*)(eap16 + (size_t)E * 8);
    int* rowptr  = ip;                 // N+2
    int* deg     = rowptr + (N + 2);   // N (cursor)
    int* bsum    = deg + N;            // 512
    int* boff    = bsum + 512;         // 512
    int* srcp    = boff + 512;         // E

    const int BLK = 256;
    const int NBLK = (N + SCAN_BLK - 1) / SCAN_BLK;

    // ---------------- ea -> fp16 + CSR build ----------------
    cvt_ea_kernel<<<(E + BLK - 1) / BLK, BLK, 0, stream>>>(ea, ea16, E);
    hipMemsetAsync(deg, 0, (size_t)N * sizeof(int), stream);
    count_kernel<<<(E + BLK - 1) / BLK, BLK, 0, stream>>>(ei, deg, E);
    scan1_kernel<<<NBLK, SCAN_BLK, 0, stream>>>(deg, rowptr, bsum, N);
    scan2_kernel<<<1, 512, 0, stream>>>(bsum, boff, NBLK);
    scan3_kernel<<<(N + BLK - 1) / BLK, BLK, 0, stream>>>(rowptr, boff, N, E);
    hipMemsetAsync(deg, 0, (size_t)N * sizeof(int), stream);
    scatterE_kernel<<<(E + BLK - 1) / BLK, BLK, 0, stream>>>(ei, rowptr, deg, srcp, E);
    permuteE_kernel<<<(E + BLK - 1) / BLK, BLK, 0, stream>>>(ei, ea16, srcp, eap16, E);

    // ------- layer 1: cin=32, H=8, C=6 (PK=16) -------
    proj8_kernel<32,6,16><<<(N*48 + BLK-1)/BLK, BLK, 0, stream>>>(
        x, wq1,bq1, wk1,bk1, wv1,bv1, wsk1,bsk1, Qb, KV16, Sb, N);
    gather8f_kernel<6,16><<<(N*8 + BLK-1)/BLK, BLK, 0, stream>>>(
        rowptr, srcp, eap16, we1, Qb, KV16, Sb, wb1, Hb, N, 1.0f/sqrtf(6.0f));

    // ------- layer 2: cin=48, H=8, C=3 (PK=8) -------
    proj8_kernel<48,3,8><<<(N*24 + BLK-1)/BLK, BLK, 0, stream>>>(
        Hb, wq2,bq2, wk2,bk2, wv2,bv2, wsk2,bsk2, Qb, KV16, Sb, N);
    gather8f_kernel<3,8><<<(N*8 + BLK-1)/BLK, BLK, 0, stream>>>(
        rowptr, srcp, eap16, we2, Qb, KV16, Sb, wb2, Hb, N, 1.0f/sqrtf(3.0f));

    // ------- layer 3: cin=24, H=1, C=64 -------
    proj64_kernel<<<(N*64 + BLK-1)/BLK, BLK, 0, stream>>>(
        Hb, wq3,bq3, wk3,bk3, wv3,bv3, wsk3,bsk3, Qb, K3, V3, Sb, N);
    gather64f_kernel<<<((size_t)N*16 + BLK-1)/BLK, BLK, 0, stream>>>(
        rowptr, srcp, eap16, we3, Qb, K3, V3, Sb, wb3, wc, bc, out, N, 1.0f/8.0f);
}